// Round 1
// baseline (267.270 us; speedup 1.0000x reference)
//
#include <hip/hip_runtime.h>
#include <hip/hip_bf16.h>

// Problem constants
#define L1C 513
#define EMBC 64
#define VC 6
#define BC 128
#define NCOLS (L1C * VC)   // 3078
#define CSC 32             // s-chunk per block (K-split granularity)
#define NTC 64             // n-columns per block tile

typedef __attribute__((ext_vector_type(8))) short short8;
typedef __attribute__((ext_vector_type(4))) float f32x4;

__device__ __forceinline__ unsigned int pack_bf16x2(float a, float b) {
    __hip_bfloat16 ha = __float2bfloat16(a);
    __hip_bfloat16 hb = __float2bfloat16(b);
    unsigned short ua, ub;
    __builtin_memcpy(&ua, &ha, 2);
    __builtin_memcpy(&ub, &hb, 2);
    return (unsigned int)ua | ((unsigned int)ub << 16);
}

// Kernel 0: out[b][v][t] = bias[t][v]  (d_out is poisoned once; we must init every call)
__global__ void init_out_kernel(float* __restrict__ out, const float* __restrict__ bias) {
    int i = blockIdx.x * 256 + threadIdx.x;
    if (i >= BC * NCOLS) return;
    int r = i % NCOLS;
    int v = r / L1C;
    int t = r - v * L1C;
    out[i] = bias[t * VC + v];
}

// Kernel 1: X[s][b][w] = bf16(emb[src[b,s], w]), w-pair-swizzled per row:
// u32 index p (= w/2) stored at p ^ ((b&7)<<2)  <=> byte offset (4p) ^ ((b&7)<<4).
// This pre-applies the LDS bank swizzle so the main kernel copies linearly.
__global__ void build_x_kernel(const int* __restrict__ src, const float* __restrict__ emb,
                               unsigned short* __restrict__ X) {
    const int s = blockIdx.x;
    const int b = threadIdx.x >> 1;     // 0..127
    const int half = threadIdx.x & 1;   // 0..1
    const int tok = src[b * L1C + s];
    const float2* e = (const float2*)(emb + tok * EMBC + half * 32);
    unsigned int* row = (unsigned int*)(X + ((size_t)s * BC + b) * EMBC);
    const int swz = (b & 7) << 2;
#pragma unroll
    for (int i = 0; i < 16; ++i) {
        float2 f = e[i];
        row[(half * 16 + i) ^ swz] = pack_bf16x2(f.x, f.y);
    }
}

// Kernel 2: per (s-chunk, n-tile) block: C[128 x 64] += sum_s X_s(128x64) @ W_s(64x64cols)
// with W elements zeroed where t > s; atomically accumulated into out.
__global__ __launch_bounds__(256) void gemm_tril_kernel(
    const float* __restrict__ Wt, const unsigned short* __restrict__ X,
    float* __restrict__ out) {
    const int tile = blockIdx.x;
    const int chunk = blockIdx.y;
    const int s0 = chunk * CSC;
    const int sEnd = min(s0 + CSC, L1C);
    const int n0 = tile * NTC;
    if (n0 >= sEnd * VC) return;   // tile entirely above the diagonal for this chunk

    __shared__ __align__(16) unsigned short Alds[BC * EMBC];   // 128 rows x 64 bf16 (swizzled image)
    __shared__ __align__(16) unsigned short Blds[NTC * EMBC];  // 64 rows (n) x 64 bf16 (w), swizzled

    const int tid = threadIdx.x;
    const int wid = tid >> 6;       // wave id 0..3
    const int lane = tid & 63;

    // --- B staging role: this thread owns column n = n0+lane, w-group wid*16..wid*16+15
    const int nl = lane;
    const int n = n0 + nl;
    const int tcol = n / VC;                       // >= 513 when n >= NCOLS -> always masked
    const size_t nsafe = (n < NCOLS) ? (size_t)n : (size_t)(NCOLS - 1);

    // --- fragment addressing
    const int h = lane >> 4;        // 0..3
    const int l15 = lane & 15;
    const int swz = (lane & 7) << 4;  // == (row&7)<<4 for every row this lane touches

    f32x4 zero = {0.f, 0.f, 0.f, 0.f};
    f32x4 acc[2][4];
#pragma unroll
    for (int i = 0; i < 2; ++i)
#pragma unroll
        for (int j = 0; j < 4; ++j) acc[i][j] = zero;

    const int sBeg = max(s0, n0 / VC);   // skip s where the whole tile is masked
    for (int s = sBeg; s < sEnd; ++s) {
        // ---- stage A: linear 16KB copy of X[s] (swizzle already embedded)
        {
            const uint4* xs = (const uint4*)(X + (size_t)s * (BC * EMBC));
            uint4* al = (uint4*)Alds;
#pragma unroll
            for (int i = 0; i < 4; ++i) al[tid + i * 256] = xs[tid + i * 256];
        }
        // ---- stage B: gather 4 consecutive w-rows at fixed n, transpose into Blds[n][w]
        {
            const bool act = (tcol <= s);
            const float* wbase = Wt + (size_t)(s * EMBC + wid * 16) * NCOLS + nsafe;
#pragma unroll
            for (int u = 0; u < 4; ++u) {
                const float* p = wbase + (size_t)(u * 4) * NCOLS;
                float f0 = p[0];
                float f1 = p[NCOLS];
                float f2 = p[2 * (size_t)NCOLS];
                float f3 = p[3 * (size_t)NCOLS];
                if (!act) { f0 = 0.f; f1 = 0.f; f2 = 0.f; f3 = 0.f; }
                uint2 packed = make_uint2(pack_bf16x2(f0, f1), pack_bf16x2(f2, f3));
                const int w = wid * 16 + u * 4;
                char* dst = (char*)Blds + nl * 128 + ((2 * w) ^ ((nl & 7) << 4));
                *(uint2*)dst = packed;
            }
        }
        __syncthreads();

        // ---- compute: 16 MFMAs per wave per s (K=64 as 2 k-steps of 32)
#pragma unroll
        for (int kk = 0; kk < 2; ++kk) {
            const int foff = (kk * 64 + h * 16) ^ swz;
            short8 a0 = *(const short8*)((const char*)Alds + (wid * 32 + l15) * 128 + foff);
            short8 a1 = *(const short8*)((const char*)Alds + (wid * 32 + 16 + l15) * 128 + foff);
#pragma unroll
            for (int nt = 0; nt < 4; ++nt) {
                short8 bb = *(const short8*)((const char*)Blds + (nt * 16 + l15) * 128 + foff);
                acc[0][nt] = __builtin_amdgcn_mfma_f32_16x16x32_bf16(a0, bb, acc[0][nt], 0, 0, 0);
                acc[1][nt] = __builtin_amdgcn_mfma_f32_16x16x32_bf16(a1, bb, acc[1][nt], 0, 0, 0);
            }
        }
        __syncthreads();
    }

    // ---- epilogue: atomic accumulate into out[b][v][t]
    // C/D layout (verified): col = lane&15 (n), row = (lane>>4)*4 + reg (b)
#pragma unroll
    for (int nt = 0; nt < 4; ++nt) {
        const int nn = n0 + nt * 16 + l15;
        if (nn >= NCOLS) continue;
        const int t = nn / VC;
        const int v = nn - t * VC;
        const size_t obase = (size_t)v * L1C + t;
#pragma unroll
        for (int ms = 0; ms < 2; ++ms) {
#pragma unroll
            for (int r = 0; r < 4; ++r) {
                const int bi = (2 * wid + ms) * 16 + h * 4 + r;
                atomicAdd(out + (size_t)bi * NCOLS + obase, acc[ms][nt][r]);
            }
        }
    }
}

extern "C" void kernel_launch(void* const* d_in, const int* in_sizes, int n_in,
                              void* d_out, int out_size, void* d_ws, size_t ws_size,
                              hipStream_t stream) {
    const int* src = (const int*)d_in[0];       // (B, L1) integer tokens
    const float* emb = (const float*)d_in[1];   // (V, EMB)
    const float* wt = (const float*)d_in[2];    // (L1, EMB, L1, V)
    const float* bias = (const float*)d_in[3];  // (L1, V)
    float* out = (float*)d_out;                 // (B, V, L1) f32
    unsigned short* X = (unsigned short*)d_ws;  // bf16 X[s][b][w], 8.4 MB

    init_out_kernel<<<(BC * NCOLS + 255) / 256, 256, 0, stream>>>(out, bias);
    build_x_kernel<<<L1C, 256, 0, stream>>>(src, emb, X);
    dim3 grid((NCOLS + NTC - 1) / NTC, (L1C + CSC - 1) / CSC);  // 49 x 17
    gemm_tril_kernel<<<grid, 256, 0, stream>>>(wt, X, out);
}

// Round 2
// 123.969 us; speedup vs baseline: 2.1559x; 2.1559x over previous
//
#include <hip/hip_runtime.h>
#include <hip/hip_bf16.h>

// Problem constants
#define L1C 513
#define EMBC 64
#define VC 6
#define BC 128
#define NCOLS (L1C * VC)                  // 3078
#define NTC 64                            // n-columns per block tile
#define NTILES ((NCOLS + NTC - 1) / NTC)  // 49

#define XELEMS ((size_t)L1C * BC * EMBC)  // bf16 elements in X
#define XBYTES (XELEMS * 2)               // 8,404,992
#define OUTELEMS ((size_t)BC * NCOLS)     // 393,984
#define OUTBYTES (OUTELEMS * 4)           // 1,575,936

typedef __attribute__((ext_vector_type(8))) short short8;
typedef __attribute__((ext_vector_type(4))) float f32x4;

__device__ __forceinline__ unsigned int pack_bf16x2(float a, float b) {
    __hip_bfloat16 ha = __float2bfloat16(a);
    __hip_bfloat16 hb = __float2bfloat16(b);
    unsigned short ua, ub;
    __builtin_memcpy(&ua, &ha, 2);
    __builtin_memcpy(&ub, &hb, 2);
    return (unsigned int)ua | ((unsigned int)ub << 16);
}

// out[b][v][t] = bias[t][v]   (only used on the atomic fallback path)
__global__ void init_out_kernel(float* __restrict__ out, const float* __restrict__ bias) {
    int i = blockIdx.x * 256 + threadIdx.x;
    if (i >= (int)OUTELEMS) return;
    int r = i % NCOLS;
    int v = r / L1C;
    int t = r - v * L1C;
    out[i] = bias[t * VC + v];
}

// X[s][b][w] = bf16(emb[src[b,s], w]), LINEAR layout (A-frags read it directly).
__global__ void build_x_kernel(const int* __restrict__ src, const float* __restrict__ emb,
                               unsigned short* __restrict__ X) {
    const int s = blockIdx.x;
    const int b = threadIdx.x >> 1;
    const int half = threadIdx.x & 1;
    const int tok = src[b * L1C + s];
    const float2* e = (const float2*)(emb + tok * EMBC + half * 32);
    unsigned int* row = (unsigned int*)(X + ((size_t)s * BC + b) * EMBC) + half * 16;
#pragma unroll
    for (int i = 0; i < 16; ++i) {
        float2 f = e[i];
        row[i] = pack_bf16x2(f.x, f.y);
    }
}

// Per (n-tile, s-chunk) block: C[128 x 64] = sum_{s in chunk, s>=t} X_s(128x64) @ W_s(64x64)
// Double-buffered B in LDS, one barrier per s. A-frags straight from global X (L2-hot).
// PARTIAL=true: coalesced stores to partial[chunk]; else atomicAdd into out (fallback).
template <bool PARTIAL>
__global__ __launch_bounds__(256) void gemm_tril_kernel(
    const float* __restrict__ Wt, const unsigned short* __restrict__ X,
    float* __restrict__ outp, int CS) {
    const int tile = blockIdx.x;
    const int chunk = blockIdx.y;
    const int n0 = tile * NTC;
    const int s0 = chunk * CS;
    const int sEnd = min(s0 + CS, L1C);

    __shared__ __align__(16) unsigned short Blds[2][NTC * EMBC];  // 2 x 8KB

    const int tid = threadIdx.x;
    const int wid = tid >> 6;
    const int lane = tid & 63;
    const int l15 = lane & 15;
    const int h = lane >> 4;

    // B-staging role: thread owns column n = n0+lane, w-rows wid*16 .. wid*16+15
    const int n = n0 + lane;
    const int tcol = n / VC;  // >= 513 for pad columns -> always masked to 0
    const size_t nsafe = (n < NCOLS) ? (size_t)n : (size_t)(NCOLS - 1);
    const int wrow0 = wid * 16;
    const int wswz = (lane & 7) << 4;

    f32x4 acc[2][4];
#pragma unroll
    for (int i = 0; i < 2; ++i)
#pragma unroll
        for (int j = 0; j < 4; ++j) acc[i][j] = f32x4{0.f, 0.f, 0.f, 0.f};

    const int sBeg = max(s0, n0 / VC);

    if (sBeg < sEnd) {
        // ---- prologue: stage B(sBeg) into buffer 0
        {
            const float* wb = Wt + ((size_t)sBeg * EMBC + wrow0) * NCOLS + nsafe;
            const bool act = (tcol <= sBeg);
            char* dstrow = (char*)Blds[0] + lane * 128;
#pragma unroll
            for (int u = 0; u < 4; ++u) {
                float f0 = wb[(size_t)(u * 4 + 0) * NCOLS];
                float f1 = wb[(size_t)(u * 4 + 1) * NCOLS];
                float f2 = wb[(size_t)(u * 4 + 2) * NCOLS];
                float f3 = wb[(size_t)(u * 4 + 3) * NCOLS];
                if (!act) { f0 = f1 = f2 = f3 = 0.f; }
                uint2 packed = make_uint2(pack_bf16x2(f0, f1), pack_bf16x2(f2, f3));
                *(uint2*)(dstrow + ((2 * (wrow0 + u * 4)) ^ wswz)) = packed;
            }
        }
        __syncthreads();

        int cur = 0;
        for (int s = sBeg; s < sEnd; ++s) {
            // ---- issue W prefetch for s+1 (clamped address; garbage never read)
            const int sn = (s + 1 < L1C) ? (s + 1) : s;
            float f[16];
            {
                const float* wb = Wt + ((size_t)sn * EMBC + wrow0) * NCOLS + nsafe;
#pragma unroll
                for (int u = 0; u < 4; ++u)
#pragma unroll
                    for (int r = 0; r < 4; ++r)
                        f[u * 4 + r] = wb[(size_t)(u * 4 + r) * NCOLS];
            }

            // ---- A fragments straight from global X (linear [s][b][w] bf16)
            const unsigned short* xrow = X + (size_t)s * (BC * EMBC);
            short8 a0k0 = *(const short8*)(xrow + (wid * 32 + l15) * EMBC + h * 8);
            short8 a0k1 = *(const short8*)(xrow + (wid * 32 + l15) * EMBC + 32 + h * 8);
            short8 a1k0 = *(const short8*)(xrow + (wid * 32 + 16 + l15) * EMBC + h * 8);
            short8 a1k1 = *(const short8*)(xrow + (wid * 32 + 16 + l15) * EMBC + 32 + h * 8);

            // ---- B frags from LDS[cur] + MFMA (16 per wave)
#pragma unroll
            for (int kk = 0; kk < 2; ++kk) {
                const int foff = (kk * 64 + h * 16) ^ ((l15 & 7) << 4);
                short8 a0 = kk ? a0k1 : a0k0;
                short8 a1 = kk ? a1k1 : a1k0;
#pragma unroll
                for (int nt = 0; nt < 4; ++nt) {
                    short8 bb = *(const short8*)((const char*)Blds[cur] + (nt * 16 + l15) * 128 + foff);
                    acc[0][nt] = __builtin_amdgcn_mfma_f32_16x16x32_bf16(a0, bb, acc[0][nt], 0, 0, 0);
                    acc[1][nt] = __builtin_amdgcn_mfma_f32_16x16x32_bf16(a1, bb, acc[1][nt], 0, 0, 0);
                }
            }

            // ---- pack + write B(s+1) into the other buffer
            {
                const bool act = (tcol <= sn);
                char* dstrow = (char*)Blds[cur ^ 1] + lane * 128;
#pragma unroll
                for (int u = 0; u < 4; ++u) {
                    float f0 = act ? f[u * 4 + 0] : 0.f;
                    float f1 = act ? f[u * 4 + 1] : 0.f;
                    float f2 = act ? f[u * 4 + 2] : 0.f;
                    float f3 = act ? f[u * 4 + 3] : 0.f;
                    uint2 packed = make_uint2(pack_bf16x2(f0, f1), pack_bf16x2(f2, f3));
                    *(uint2*)(dstrow + ((2 * (wrow0 + u * 4)) ^ wswz)) = packed;
                }
            }
            __syncthreads();
            cur ^= 1;
        }
    }

    // ---- epilogue
    // C/D layout (verified r1): col = l15 (n), row-in-16 = h*4 + reg
#pragma unroll
    for (int nt = 0; nt < 4; ++nt) {
        const int nn = n0 + nt * 16 + l15;
        if (nn >= NCOLS) continue;
        if (PARTIAL) {
            float* dst = outp + (size_t)chunk * OUTELEMS;
#pragma unroll
            for (int ms = 0; ms < 2; ++ms)
#pragma unroll
                for (int r = 0; r < 4; ++r) {
                    const int bi = wid * 32 + ms * 16 + h * 4 + r;
                    dst[(size_t)bi * NCOLS + nn] = acc[ms][nt][r];
                }
        } else {
            const int t = nn / VC;
            const int v = nn - t * VC;
            const size_t obase = (size_t)v * L1C + t;
#pragma unroll
            for (int ms = 0; ms < 2; ++ms)
#pragma unroll
                for (int r = 0; r < 4; ++r) {
                    const int bi = wid * 32 + ms * 16 + h * 4 + r;
                    atomicAdd(outp + (size_t)bi * NCOLS + obase, acc[ms][nt][r]);
                }
        }
    }
}

// out[b][v][t] = bias[n] + sum_c partial[c][b][n],  n = t*6+v
__global__ void reduce_kernel(const float* __restrict__ partial, const float* __restrict__ bias,
                              float* __restrict__ out, int nchunks) {
    int i = blockIdx.x * 256 + threadIdx.x;  // i = b*NCOLS + n
    if (i >= (int)OUTELEMS) return;
    int b = i / NCOLS;
    int nn = i - b * NCOLS;
    float sum = bias[nn];
    for (int c = 0; c < nchunks; ++c) sum += partial[(size_t)c * OUTELEMS + i];
    int t = nn / VC;
    int v = nn - t * VC;
    out[(size_t)b * NCOLS + (size_t)v * L1C + t] = sum;
}

extern "C" void kernel_launch(void* const* d_in, const int* in_sizes, int n_in,
                              void* d_out, int out_size, void* d_ws, size_t ws_size,
                              hipStream_t stream) {
    const int* src = (const int*)d_in[0];
    const float* emb = (const float*)d_in[1];
    const float* wt = (const float*)d_in[2];
    const float* bias = (const float*)d_in[3];
    float* out = (float*)d_out;
    unsigned short* X = (unsigned short*)d_ws;

    build_x_kernel<<<L1C, 256, 0, stream>>>(src, emb, X);

    size_t avail = (ws_size > XBYTES) ? (ws_size - XBYTES) : 0;
    int nchunks = (int)(avail / OUTBYTES);
    if (nchunks > 17) nchunks = 17;

    if (nchunks >= 2) {
        // split-K with partials in scratch, no atomics
        int CS = (L1C + nchunks - 1) / nchunks;
        nchunks = (L1C + CS - 1) / CS;  // drop empty chunks
        float* partial = (float*)((char*)d_ws + XBYTES);
        dim3 grid(NTILES, nchunks);
        gemm_tril_kernel<true><<<grid, 256, 0, stream>>>(wt, X, partial, CS);
        int rblocks = (int)((OUTELEMS + 255) / 256);
        reduce_kernel<<<rblocks, 256, 0, stream>>>(partial, bias, out, nchunks);
    } else {
        // scratch too small: atomic fallback (round-1 verified path)
        init_out_kernel<<<(int)((OUTELEMS + 255) / 256), 256, 0, stream>>>(out, bias);
        dim3 grid(NTILES, 17);
        gemm_tril_kernel<false><<<grid, 256, 0, stream>>>(wt, X, out, 31);
    }
}

// Round 3
// 93.117 us; speedup vs baseline: 2.8703x; 1.3313x over previous
//
#include <hip/hip_runtime.h>
#include <hip/hip_bf16.h>

// Problem constants
#define L1C 513
#define EMBC 64
#define VC 6
#define BC 128
#define NCOLS (L1C * VC)                  // 3078
#define NTC 64                            // n-columns per block tile
#define NTILES ((NCOLS + NTC - 1) / NTC)  // 49

#define XELEMS ((size_t)L1C * BC * EMBC)  // bf16 elements in X
#define XBYTES (XELEMS * 2)               // 8,404,992 (16B aligned)
#define OUTELEMS ((size_t)BC * NCOLS)     // 393,984
#define PARTBYTES (OUTELEMS * 2)          // bf16 partials per chunk

typedef __attribute__((ext_vector_type(8))) short short8;
typedef __attribute__((ext_vector_type(4))) float f32x4;

__device__ __forceinline__ unsigned int pack_bf16x2(float a, float b) {
    __hip_bfloat16 ha = __float2bfloat16(a);
    __hip_bfloat16 hb = __float2bfloat16(b);
    unsigned short ua, ub;
    __builtin_memcpy(&ua, &ha, 2);
    __builtin_memcpy(&ub, &hb, 2);
    return (unsigned int)ua | ((unsigned int)ub << 16);
}

__device__ __forceinline__ unsigned short bf16bits(float a) {
    __hip_bfloat16 h = __float2bfloat16(a);
    unsigned short u;
    __builtin_memcpy(&u, &h, 2);
    return u;
}

// out[b][v][t] = bias[t][v]   (atomic-fallback path only)
__global__ void init_out_kernel(float* __restrict__ out, const float* __restrict__ bias) {
    int i = blockIdx.x * 256 + threadIdx.x;
    if (i >= (int)OUTELEMS) return;
    int r = i % NCOLS;
    int v = r / L1C;
    int t = r - v * L1C;
    out[i] = bias[t * VC + v];
}

// X[s][b][w] = bf16(emb[src[b,s], w]), linear layout
__global__ void build_x_kernel(const int* __restrict__ src, const float* __restrict__ emb,
                               unsigned short* __restrict__ X) {
    const int s = blockIdx.x;
    const int b = threadIdx.x >> 1;
    const int half = threadIdx.x & 1;
    const int tok = src[b * L1C + s];
    const float2* e = (const float2*)(emb + tok * EMBC + half * 32);
    unsigned int* row = (unsigned int*)(X + ((size_t)s * BC + b) * EMBC) + half * 16;
#pragma unroll
    for (int i = 0; i < 16; ++i) {
        float2 f = e[i];
        row[i] = pack_bf16x2(f.x, f.y);
    }
}

// Per (n-tile, s-chunk) block: C[128 x 64] = sum_{s in chunk, s>=t} X_s(128x64) @ W_s(64x64)
// 2-deep W register pipeline + 1-deep A prefetch; one barrier per s.
template <bool PARTIAL>
__global__ __launch_bounds__(256) void gemm_tril_kernel(
    const float* __restrict__ Wt, const unsigned short* __restrict__ X,
    void* __restrict__ outp, int CS) {
    const int tile = blockIdx.x;
    const int chunk = blockIdx.y;
    const int n0 = tile * NTC;
    const int s0 = chunk * CS;
    const int sEnd = min(s0 + CS, L1C);

    __shared__ __align__(16) unsigned short Blds[2][NTC * EMBC];  // 2 x 8KB

    const int tid = threadIdx.x;
    const int wid = tid >> 6;
    const int lane = tid & 63;
    const int l15 = lane & 15;
    const int h = lane >> 4;

    const int n = n0 + lane;
    const int tcol = n / VC;  // pad columns (n>=NCOLS) give tcol>=513 -> always masked
    const size_t nsafe = (n < NCOLS) ? (size_t)n : (size_t)(NCOLS - 1);
    const int wrow0 = wid * 16;
    const int wswz = (lane & 7) << 4;

    f32x4 acc[2][4];
#pragma unroll
    for (int i = 0; i < 2; ++i)
#pragma unroll
        for (int j = 0; j < 4; ++j) acc[i][j] = f32x4{0.f, 0.f, 0.f, 0.f};

    const int sBeg = max(s0, n0 / VC);

#define ISSUEW(ss, farr)                                                         \
    {                                                                            \
        const int scl_ = ((ss) < L1C) ? (ss) : (L1C - 1);                        \
        const float* wb_ = Wt + ((size_t)scl_ * EMBC + wrow0) * NCOLS + nsafe;   \
        _Pragma("unroll") for (int u_ = 0; u_ < 16; ++u_)                        \
            farr[u_] = wb_[(size_t)u_ * NCOLS];                                  \
    }

#define PACKW(ss, farr, buf)                                                     \
    {                                                                            \
        const bool act_ = (tcol <= (ss));                                        \
        char* dr_ = (char*)Blds[buf] + lane * 128;                               \
        _Pragma("unroll") for (int u_ = 0; u_ < 4; ++u_) {                       \
            float g0 = act_ ? farr[u_ * 4 + 0] : 0.f;                            \
            float g1 = act_ ? farr[u_ * 4 + 1] : 0.f;                            \
            float g2 = act_ ? farr[u_ * 4 + 2] : 0.f;                            \
            float g3 = act_ ? farr[u_ * 4 + 3] : 0.f;                            \
            uint2 pk_ = make_uint2(pack_bf16x2(g0, g1), pack_bf16x2(g2, g3));    \
            *(uint2*)(dr_ + ((2 * (wrow0 + u_ * 4)) ^ wswz)) = pk_;              \
        }                                                                        \
    }

#define ISSUEA(ss, aarr)                                                             \
    {                                                                                \
        const int scl_ = ((ss) < L1C) ? (ss) : (L1C - 1);                            \
        const unsigned short* xr_ = X + (size_t)scl_ * (BC * EMBC);                  \
        aarr[0] = *(const short8*)(xr_ + (wid * 32 + l15) * EMBC + h * 8);           \
        aarr[1] = *(const short8*)(xr_ + (wid * 32 + l15) * EMBC + 32 + h * 8);      \
        aarr[2] = *(const short8*)(xr_ + (wid * 32 + 16 + l15) * EMBC + h * 8);      \
        aarr[3] = *(const short8*)(xr_ + (wid * 32 + 16 + l15) * EMBC + 32 + h * 8); \
    }

#define MFMASTEP(aarr, buf)                                                                              \
    {                                                                                                    \
        _Pragma("unroll") for (int kk_ = 0; kk_ < 2; ++kk_) {                                            \
            const int foff_ = (kk_ * 64 + h * 16) ^ ((l15 & 7) << 4);                                    \
            _Pragma("unroll") for (int nt_ = 0; nt_ < 4; ++nt_) {                                        \
                short8 bb_ = *(const short8*)((const char*)Blds[buf] + (nt_ * 16 + l15) * 128 + foff_);  \
                acc[0][nt_] = __builtin_amdgcn_mfma_f32_16x16x32_bf16(aarr[kk_], bb_, acc[0][nt_], 0, 0, 0);     \
                acc[1][nt_] = __builtin_amdgcn_mfma_f32_16x16x32_bf16(aarr[2 + kk_], bb_, acc[1][nt_], 0, 0, 0); \
            }                                                                                            \
        }                                                                                                \
    }

    if (sBeg < sEnd) {
        float fW0[16], fW1[16];
        short8 aC[4], aN[4];
        // prologue: stage B(sBeg) into buf0; issue W(sBeg+1) and A(sBeg)
        {
            float fP[16];
            ISSUEW(sBeg, fP);
            PACKW(sBeg, fP, 0);
        }
        ISSUEW(sBeg + 1, fW0);
        ISSUEA(sBeg, aC);
        __syncthreads();

        int s = sBeg, cur = 0;
        while (true) {
            // iter even: consume fW0/aC, issue fW1/aN
            ISSUEW(s + 2, fW1);
            ISSUEA(s + 1, aN);
            MFMASTEP(aC, cur);
            PACKW(s + 1, fW0, cur ^ 1);
            __syncthreads();
            cur ^= 1;
            ++s;
            if (s >= sEnd) break;

            // iter odd: consume fW1/aN, issue fW0/aC
            ISSUEW(s + 2, fW0);
            ISSUEA(s + 1, aC);
            MFMASTEP(aN, cur);
            PACKW(s + 1, fW1, cur ^ 1);
            __syncthreads();
            cur ^= 1;
            ++s;
            if (s >= sEnd) break;
        }
    }

    // epilogue — C/D layout (verified): col = l15 (n), row-in-16 = h*4 + reg
#pragma unroll
    for (int nt = 0; nt < 4; ++nt) {
        const int nn = n0 + nt * 16 + l15;
        if (nn >= NCOLS) continue;
        if (PARTIAL) {
            unsigned short* dst = (unsigned short*)outp + (size_t)chunk * OUTELEMS;
#pragma unroll
            for (int ms = 0; ms < 2; ++ms)
#pragma unroll
                for (int r = 0; r < 4; ++r) {
                    const int bi = wid * 32 + ms * 16 + h * 4 + r;
                    dst[(size_t)bi * NCOLS + nn] = bf16bits(acc[ms][nt][r]);
                }
        } else {
            float* dst = (float*)outp;
            const int t = nn / VC;
            const int v = nn - t * VC;
            const size_t obase = (size_t)v * L1C + t;
#pragma unroll
            for (int ms = 0; ms < 2; ++ms)
#pragma unroll
                for (int r = 0; r < 4; ++r) {
                    const int bi = wid * 32 + ms * 16 + h * 4 + r;
                    atomicAdd(dst + (size_t)bi * NCOLS + obase, acc[ms][nt][r]);
                }
        }
    }
#undef ISSUEW
#undef PACKW
#undef ISSUEA
#undef MFMASTEP
}

// out[b][v][t] = bias[n] + sum_c bf16 partial[c][b][n],  n = t*6+v
__global__ void reduce_kernel(const unsigned short* __restrict__ partial,
                              const float* __restrict__ bias,
                              float* __restrict__ out, int nchunks) {
    int i4 = blockIdx.x * 256 + threadIdx.x;
    if (i4 >= (int)(OUTELEMS / 4)) return;
    const size_t base = (size_t)i4 * 4;
    float sum[4];
#pragma unroll
    for (int j = 0; j < 4; ++j) {
        int idx = (int)base + j;
        sum[j] = bias[idx % NCOLS];
    }
    for (int c = 0; c < nchunks; ++c) {
        const ushort4 p = *(const ushort4*)(partial + (size_t)c * OUTELEMS + base);
        unsigned int u0 = (unsigned int)p.x << 16, u1 = (unsigned int)p.y << 16;
        unsigned int u2 = (unsigned int)p.z << 16, u3 = (unsigned int)p.w << 16;
        float f0, f1, f2, f3;
        __builtin_memcpy(&f0, &u0, 4);
        __builtin_memcpy(&f1, &u1, 4);
        __builtin_memcpy(&f2, &u2, 4);
        __builtin_memcpy(&f3, &u3, 4);
        sum[0] += f0;
        sum[1] += f1;
        sum[2] += f2;
        sum[3] += f3;
    }
#pragma unroll
    for (int j = 0; j < 4; ++j) {
        int idx = (int)base + j;
        int b = idx / NCOLS;
        int nn = idx - b * NCOLS;
        int t = nn / VC;
        int v = nn - t * VC;
        out[(size_t)b * NCOLS + (size_t)v * L1C + t] = sum[j];
    }
}

extern "C" void kernel_launch(void* const* d_in, const int* in_sizes, int n_in,
                              void* d_out, int out_size, void* d_ws, size_t ws_size,
                              hipStream_t stream) {
    const int* src = (const int*)d_in[0];
    const float* emb = (const float*)d_in[1];
    const float* wt = (const float*)d_in[2];
    const float* bias = (const float*)d_in[3];
    float* out = (float*)d_out;
    unsigned short* X = (unsigned short*)d_ws;

    build_x_kernel<<<L1C, 256, 0, stream>>>(src, emb, X);

    size_t avail = (ws_size > XBYTES) ? (ws_size - XBYTES) : 0;
    int nchunks = (int)(avail / PARTBYTES);
    if (nchunks > 31) nchunks = 31;  // CS=17 target

    if (nchunks >= 2) {
        int CS = (L1C + nchunks - 1) / nchunks;
        nchunks = (L1C + CS - 1) / CS;
        unsigned short* partial = (unsigned short*)((char*)d_ws + XBYTES);
        dim3 grid(NTILES, nchunks);
        gemm_tril_kernel<true><<<grid, 256, 0, stream>>>(wt, X, (void*)partial, CS);
        reduce_kernel<<<(int)((OUTELEMS / 4 + 255) / 256), 256, 0, stream>>>(partial, bias, out, nchunks);
    } else {
        // scratch too small: atomic fallback
        init_out_kernel<<<(int)((OUTELEMS + 255) / 256), 256, 0, stream>>>(out, bias);
        dim3 grid(NTILES, 17);
        gemm_tril_kernel<false><<<grid, 256, 0, stream>>>(wt, X, (void*)out, 31);
    }
}